// Round 1
// baseline (302.698 us; speedup 1.0000x reference)
//
#include <hip/hip_runtime.h>
#include <stdint.h>

#define NB 8
#define NPRED 25200
#define NTOP 1000
#define NCLS 80
#define CONF_T 0.25f
#define IOU_THR 0.45f
#define MAXWH 4096.0f
#define CAP 2048

// ---------------------------------------------------------------------------
// K1: per-prediction score = obj * max(cls), argmax cls (first-occurrence),
// masked score (> CONF ? score : -1). Coalesced float4 -> LDS staging.
// ---------------------------------------------------------------------------
__global__ __launch_bounds__(128) void k_score(const float* __restrict__ x,
                                               float* __restrict__ msc,
                                               int* __restrict__ cls) {
#pragma clang fp contract(off)
    __shared__ float sm[128 * 85];
    const float4* x4 = (const float4*)x;
    const int tile4 = 128 * 85 / 4;  // 2720 float4 per tile (exact)
    long long base4 = (long long)blockIdx.x * tile4;
    for (int k = 0; k < tile4; k += 128) {
        int fi = k + (int)threadIdx.x;
        if (fi < tile4) {
            float4 v = x4[base4 + fi];
            int o = fi * 4;
            sm[o] = v.x; sm[o + 1] = v.y; sm[o + 2] = v.z; sm[o + 3] = v.w;
        }
    }
    __syncthreads();
    // grid is exactly 1575*128 = 201600 preds; no tail
    int q = blockIdx.x * 128 + threadIdx.x;
    const float* p = &sm[threadIdx.x * 85];  // stride 85: 2-way bank alias (free)
    float obj = p[4];
    float best = p[5];
    int bid = 0;
    for (int c = 1; c < NCLS; ++c) {
        float v = p[5 + c];
        if (v > best) { best = v; bid = c; }  // strict > : first occurrence wins
    }
    float score = obj * best;
    msc[q] = (score > CONF_T) ? score : -1.0f;
    cls[q] = bid;
}

// ---------------------------------------------------------------------------
// K2: per-batch top-1000 via histogram-select + LDS bitonic sort of <=2048
// candidates. Key = (~score_bits << 32) | idx : ascending sort gives
// descending score, ascending index on ties (stable top_k semantics).
// ---------------------------------------------------------------------------
__global__ __launch_bounds__(256) void k_topk(const float* __restrict__ x,
                                              const float* __restrict__ msc,
                                              const int* __restrict__ cls,
                                              float* __restrict__ det,
                                              float* __restrict__ offb,
                                              unsigned* __restrict__ valid) {
#pragma clang fp contract(off)
    __shared__ unsigned hist[1025];
    __shared__ unsigned long long keys[CAP];
    __shared__ unsigned scnt;
    __shared__ int sB;
    const int b = blockIdx.x;
    const int t = threadIdx.x;
    const float* ms = msc + (size_t)b * NPRED;

    for (int i = t; i < 1025; i += 256) hist[i] = 0;
    if (t == 0) scnt = 0;
    __syncthreads();

    // Phase 1: histogram of score float-bits >> 14 (bins for (0.25, 1.0])
    for (int p = t; p < NPRED; p += 256) {
        float s = ms[p];
        if (s > CONF_T) {
            int bin = (int)(__float_as_uint(s) >> 14) - 0xFA00;
            bin = bin < 0 ? 0 : (bin > 1024 ? 1024 : bin);
            atomicAdd(&hist[bin], 1u);
        }
    }
    __syncthreads();

    // Phase 2: find boundary bin B (cumulative-from-top >= 1000)
    if (t == 0) {
        unsigned run = 0;
        int B = 0;
        for (int i = 1024; i >= 0; --i) {
            run += hist[i];
            if (run >= NTOP) { B = i; break; }
        }
        sB = B;
    }
    __syncthreads();
    const int B = sB;

    // Phase 3: compact all candidates in bins >= B
    for (int p = t; p < NPRED; p += 256) {
        float s = ms[p];
        if (s > CONF_T) {
            unsigned bits = __float_as_uint(s);
            int bin = (int)(bits >> 14) - 0xFA00;
            bin = bin < 0 ? 0 : (bin > 1024 ? 1024 : bin);
            if (bin >= B) {
                unsigned slot = atomicAdd(&scnt, 1u);
                if (slot < CAP)
                    keys[slot] = ((unsigned long long)(~bits) << 32) | (unsigned)p;
            }
        }
    }
    __syncthreads();
    unsigned cnt = scnt; if (cnt > CAP) cnt = CAP;
    for (int i = (int)cnt + t; i < CAP; i += 256) keys[i] = ~0ULL;  // sorts last
    __syncthreads();

    // Phase 4: bitonic sort CAP keys ascending
    for (unsigned k = 2; k <= CAP; k <<= 1) {
        for (unsigned j = k >> 1; j > 0; j >>= 1) {
            for (unsigned tt = (unsigned)t; tt < CAP / 2; tt += 256) {
                unsigned i = ((tt & ~(j - 1)) << 1) | (tt & (j - 1));
                unsigned pi = i | j;
                bool up = ((i & k) == 0);
                unsigned long long a = keys[i], c2 = keys[pi];
                bool sw = up ? (a > c2) : (a < c2);
                if (sw) { keys[i] = c2; keys[pi] = a; }
            }
            __syncthreads();
        }
    }

    // Phase 5: gather top-1000 -> det rows, class-offset boxes, valid flags
    for (int r = t; r < NTOP; r += 256) {
        unsigned long long key = keys[r];
        unsigned p = (unsigned)key;
        float score = __uint_as_float(~(unsigned)(key >> 32));
        bool v = score > CONF_T;
        float o0 = 0, o1 = 0, o2 = 0, o3 = 0, o4 = 0, o5 = 0;
        float f0 = 0, f1 = 0, f2 = 0, f3 = 0;
        if (v) {
            const float* xp = x + ((size_t)b * NPRED + p) * 85;
            float xc = xp[0], yc = xp[1], w = xp[2], h = xp[3];
            float hw = w * 0.5f, hh = h * 0.5f;   // mul then sub/add: matches numpy
            o0 = xc - hw; o1 = yc - hh; o2 = xc + hw; o3 = yc + hh;
            o4 = score;
            float cf = (float)cls[(size_t)b * NPRED + p];
            o5 = cf;
            float co = cf * MAXWH;
            f0 = o0 + co; f1 = o1 + co; f2 = o2 + co; f3 = o3 + co;
        }
        size_t d6 = ((size_t)b * NTOP + r) * 6;
        det[d6 + 0] = o0; det[d6 + 1] = o1; det[d6 + 2] = o2;
        det[d6 + 3] = o3; det[d6 + 4] = o4; det[d6 + 5] = o5;
        size_t d4 = ((size_t)b * NTOP + r) * 4;
        offb[d4 + 0] = f0; offb[d4 + 1] = f1; offb[d4 + 2] = f2; offb[d4 + 3] = f3;
        valid[(size_t)b * NTOP + r] = v ? 1u : 0u;
    }
}

// ---------------------------------------------------------------------------
// K3: 1000x1000 IoU suppression bitmask per batch (16 u64 words per row).
// Bit set iff iou(row, col) > 0.45 and col != row (diagonal zeroed like ref).
// ---------------------------------------------------------------------------
__global__ __launch_bounds__(256) void k_iou(const float* __restrict__ offb,
                                             unsigned long long* __restrict__ mask) {
#pragma clang fp contract(off)
    __shared__ float bx[NTOP * 4];
    int b = blockIdx.x >> 4;   // grid = 8 batches * 16 row-groups
    int rg = blockIdx.x & 15;
    const float* ob = offb + (size_t)b * NTOP * 4;
    for (int i = threadIdx.x; i < NTOP * 4; i += 256) bx[i] = ob[i];
    __syncthreads();
    for (int cell = threadIdx.x; cell < 1024; cell += 256) {
        int i = rg * 64 + (cell >> 4);
        int w = cell & 15;
        if (i >= NTOP) continue;
        float ax1 = bx[i * 4 + 0], ay1 = bx[i * 4 + 1];
        float ax2 = bx[i * 4 + 2], ay2 = bx[i * 4 + 3];
        float areaA = (ax2 - ax1) * (ay2 - ay1);
        unsigned long long bitsw = 0;
        int c0 = w * 64;
        for (int cc = 0; cc < 64; ++cc) {
            int c = c0 + cc;
            if (c >= NTOP) break;
            float b1 = bx[c * 4 + 0], b2 = bx[c * 4 + 1];
            float b3 = bx[c * 4 + 2], b4 = bx[c * 4 + 3];
            float ltx = fmaxf(ax1, b1), lty = fmaxf(ay1, b2);
            float rbx = fminf(ax2, b3), rby = fminf(ay2, b4);
            float ww = fmaxf(rbx - ltx, 0.0f), hh = fmaxf(rby - lty, 0.0f);
            float inter = ww * hh;
            float areaB = (b3 - b1) * (b4 - b2);
            float iou = inter / (((areaA + areaB) - inter) + 1e-9f);  // np assoc order
            if (iou > IOU_THR && c != i) bitsw |= (1ULL << cc);
        }
        mask[((size_t)b * NTOP + i) * 16 + w] = bitsw;
    }
}

// ---------------------------------------------------------------------------
// K4: sequential greedy scan (one wave per batch) + masked output write.
// Lane tt of group g owns row g*64+tt (16 mask words in regs). Per group:
// cross-lane OR builds the suppression word, then a 64-step pure-ALU chain.
// ---------------------------------------------------------------------------
__device__ __forceinline__ unsigned long long shfl_xor_u64(unsigned long long v, int m) {
    int lo = __shfl_xor((int)(unsigned)v, m);
    int hi = __shfl_xor((int)(unsigned)(v >> 32), m);
    return ((unsigned long long)(unsigned)hi << 32) | (unsigned)lo;
}

__global__ __launch_bounds__(64) void k_scan(const unsigned long long* __restrict__ mask,
                                             const unsigned* __restrict__ valid,
                                             const float* __restrict__ det,
                                             float* __restrict__ out) {
    int b = blockIdx.x;
    int lane = threadIdx.x;
    const unsigned long long* mb = mask + (size_t)b * NTOP * 16;
    __shared__ unsigned long long colw[64];
    unsigned long long acc[16];
    unsigned long long kw[16];
#pragma unroll
    for (int w = 0; w < 16; ++w) acc[w] = 0;

#pragma unroll
    for (int g = 0; g < 16; ++g) {
        int r = g * 64 + lane;
        unsigned long long myrow[16];
        if (r < NTOP) {
            const unsigned long long* rp = mb + (size_t)r * 16;
#pragma unroll
            for (int w = 0; w < 16; ++w) myrow[w] = rp[w];
        } else {
#pragma unroll
            for (int w = 0; w < 16; ++w) myrow[w] = 0;
        }
        unsigned vflag = (r < NTOP) ? valid[(size_t)b * NTOP + r] : 0u;
        unsigned long long vb = __ballot(vflag != 0);

        // suppression word for this group from all previously-kept rows
        unsigned long long S = acc[g];
        S |= shfl_xor_u64(S, 1);  S |= shfl_xor_u64(S, 2);  S |= shfl_xor_u64(S, 4);
        S |= shfl_xor_u64(S, 8);  S |= shfl_xor_u64(S, 16); S |= shfl_xor_u64(S, 32);

        colw[lane] = myrow[g];
        __syncthreads();

        unsigned long long kb = 0;
        int lim = (g == 15) ? (NTOP - 15 * 64) : 64;
#pragma unroll 4
        for (int tt = 0; tt < 64; ++tt) {
            if (tt >= lim) break;
            unsigned long long m = colw[tt];          // broadcast read, prefetchable
            bool sup = (S >> tt) & 1ULL;
            bool keep = (!sup) && ((vb >> tt) & 1ULL);
            S |= keep ? m : 0ULL;                     // serial chain: pure ALU
            kb |= keep ? (1ULL << tt) : 0ULL;
        }
        kw[g] = kb;
        bool mykeep = (kb >> lane) & 1ULL;
#pragma unroll
        for (int w = 0; w < 16; ++w) acc[w] |= mykeep ? myrow[w] : 0ULL;
        __syncthreads();
    }

    // masked output write (all 1000*6 elements per batch, every call)
    const float* dt = det + (size_t)b * NTOP * 6;
    float* ob = out + (size_t)b * NTOP * 6;
#pragma unroll
    for (int g = 0; g < 16; ++g) {
        int r = g * 64 + lane;
        if (r < NTOP) {
            bool keep = (kw[g] >> lane) & 1ULL;
#pragma unroll
            for (int c = 0; c < 6; ++c) {
                float v = dt[r * 6 + c];
                ob[r * 6 + c] = keep ? v : 0.0f;
            }
        }
    }
}

// ---------------------------------------------------------------------------
extern "C" void kernel_launch(void* const* d_in, const int* in_sizes, int n_in,
                              void* d_out, int out_size, void* d_ws, size_t ws_size,
                              hipStream_t stream) {
    const float* x = (const float*)d_in[0];
    char* ws = (char*)d_ws;
    // ws layout (bytes): all 16B aligned; total 2,988,800 B
    float* msc = (float*)(ws);                              //   806,400
    int* cls = (int*)(ws + 806400);                         //   806,400
    float* det = (float*)(ws + 1612800);                    //   192,000
    float* offb = (float*)(ws + 1804800);                   //   128,000
    unsigned* valid = (unsigned*)(ws + 1932800);            //    32,000
    unsigned long long* mask = (unsigned long long*)(ws + 1964800);  // 1,024,000

    k_score<<<1575, 128, 0, stream>>>(x, msc, cls);         // 1575*128 = 201600 preds
    k_topk<<<NB, 256, 0, stream>>>(x, msc, cls, det, offb, valid);
    k_iou<<<NB * 16, 256, 0, stream>>>(offb, mask);
    k_scan<<<NB, 64, 0, stream>>>(mask, valid, det, (float*)d_out);
}

// Round 2
// 242.045 us; speedup vs baseline: 1.2506x; 1.2506x over previous
//
#include <hip/hip_runtime.h>
#include <stdint.h>

#define NB 8
#define NPRED 25200
#define NTOP 1000
#define NCLS 80
#define CONF_T 0.25f
#define IOU_THR 0.45f
#define MAXWH 4096.0f
#define CAP 2048
#define NBINS 1025
#define SBLK 128
#define SBPB 197   // ceil(25200/128): 197*128 = 25216

typedef unsigned long long u64;

// ---------------------------------------------------------------------------
// K1: score/class per pred + global histogram of score bits.
// Staging via global_load_lds width=16 (no VGPR round trip).
// ---------------------------------------------------------------------------
__global__ __launch_bounds__(128) void k_score(const float* __restrict__ x,
                                               float* __restrict__ msc,
                                               int* __restrict__ cls,
                                               unsigned* __restrict__ hist) {
#pragma clang fp contract(off)
    __shared__ __align__(16) float sm[SBLK * 85];
    const int b = blockIdx.x / SBPB;
    const int blk = blockIdx.x % SBPB;
    const int t = threadIdx.x;
    const int wave = t >> 6, lane = t & 63;
    const long long TOT4 = (long long)NB * NPRED * 85 / 4;  // 4,284,000
    const long long base4 = ((long long)b * NPRED + (long long)blk * SBLK) * 85 / 4;
    const float4* x4 = (const float4*)x;
    const int tile4 = SBLK * 85 / 4;  // 2720

    for (int k = 0; k < 22; ++k) {
        int ib = k * 128 + wave * 64;      // wave-uniform lds base (in float4 units)
        int fi = ib + lane;
        if (fi < tile4) {
            long long gi = base4 + fi;
            if (gi >= TOT4) gi = TOT4 - 1;  // tail clamp (outputs guarded below)
            __builtin_amdgcn_global_load_lds(
                (const __attribute__((address_space(1))) void*)(x4 + gi),
                (__attribute__((address_space(3))) void*)(sm + (size_t)ib * 4),
                16, 0, 0);
        }
    }
    __syncthreads();

    int pred = blk * SBLK + t;
    if (pred < NPRED) {
        const float* p = &sm[t * 85];
        float obj = p[4];
        float best = p[5];
        int bid = 0;
        for (int c = 1; c < NCLS; ++c) {
            float v = p[5 + c];
            if (v > best) { best = v; bid = c; }  // strict >: first occurrence
        }
        float score = obj * best;
        int q = b * NPRED + pred;
        msc[q] = (score > CONF_T) ? score : -1.0f;
        cls[q] = bid;
        if (score > CONF_T) {
            int bin = (int)(__float_as_uint(score) >> 14) - 0xFA00;
            bin = bin < 0 ? 0 : (bin > 1024 ? 1024 : bin);
            atomicAdd(&hist[b * NBINS + bin], 1u);
        }
    }
}

// ---------------------------------------------------------------------------
// K2: per-batch boundary bin B (suffix count >= 1000). 8 waves, wave = batch.
// ---------------------------------------------------------------------------
__global__ __launch_bounds__(512) void k_boundary(const unsigned* __restrict__ hist,
                                                  int* __restrict__ Bv) {
    int b = threadIdx.x >> 6, lane = threadIdx.x & 63;
    const unsigned* h = hist + b * NBINS;
    int hi = 1024 - 16 * lane;           // lane's chunk: bins [hi-15, hi]
    unsigned sum = 0;
    for (int k = 0; k < 16; ++k) sum += h[hi - k];
    if (lane == 63) sum += h[0];
    unsigned v = sum;
    for (int d = 1; d < 64; d <<= 1) {
        unsigned o = __shfl_up(v, d);
        if (lane >= d) v += o;
    }
    unsigned excl = v - sum;             // count strictly above my chunk
    u64 ball = __ballot(v >= NTOP);
    int B = 0;
    if (ball != 0) {
        int sel = __builtin_ctzll(ball);
        if (lane == sel) {
            unsigned run = excl;
            for (int k = 0; k < 16; ++k) {
                run += h[hi - k];
                if (run >= NTOP) { B = hi - k; break; }
            }
        }
        B = __shfl(B, sel);
    }
    if (lane == 0) Bv[b] = B;
}

// ---------------------------------------------------------------------------
// K3: compact candidates (bin >= B) with one pred per thread.
// ---------------------------------------------------------------------------
__global__ __launch_bounds__(256) void k_compact(const float* __restrict__ msc,
                                                 const int* __restrict__ Bv,
                                                 unsigned* __restrict__ cnt,
                                                 u64* __restrict__ cand) {
    int b = blockIdx.x / 99;
    int p = (blockIdx.x % 99) * 256 + threadIdx.x;
    if (p >= NPRED) return;
    float s = msc[(size_t)b * NPRED + p];
    if (s > CONF_T) {
        unsigned bits = __float_as_uint(s);
        int bin = (int)(bits >> 14) - 0xFA00;
        bin = bin < 0 ? 0 : (bin > 1024 ? 1024 : bin);
        if (bin >= Bv[b]) {
            unsigned slot = atomicAdd(&cnt[b], 1u);
            if (slot < CAP)
                cand[(size_t)b * CAP + slot] = ((u64)(~bits) << 32) | (unsigned)p;
        }
    }
}

// ---------------------------------------------------------------------------
// K4: per-batch bitonic sort of <=2048 candidates (1024 threads, 1 CE each)
// then gather top-1000 -> det rows, class-offset boxes, valid flags.
// ---------------------------------------------------------------------------
__global__ __launch_bounds__(1024) void k_sort(const float* __restrict__ x,
                                               const int* __restrict__ cls,
                                               const unsigned* __restrict__ cnt,
                                               const u64* __restrict__ cand,
                                               float* __restrict__ det,
                                               float* __restrict__ offb,
                                               unsigned* __restrict__ valid) {
#pragma clang fp contract(off)
    __shared__ u64 keys[CAP];
    const int b = blockIdx.x, t = threadIdx.x;
    unsigned c = cnt[b]; if (c > CAP) c = CAP;
    for (int i = t; i < CAP; i += 1024)
        keys[i] = (i < (int)c) ? cand[(size_t)b * CAP + i] : ~0ULL;
    __syncthreads();
    for (unsigned k = 2; k <= CAP; k <<= 1) {
        for (unsigned j = k >> 1; j > 0; j >>= 1) {
            unsigned i = (((unsigned)t & ~(j - 1)) << 1) | ((unsigned)t & (j - 1));
            unsigned pi = i | j;
            bool up = ((i & k) == 0);
            u64 a = keys[i], d = keys[pi];
            bool sw = up ? (a > d) : (a < d);
            if (sw) { keys[i] = d; keys[pi] = a; }
            __syncthreads();
        }
    }
    if (t < NTOP) {
        u64 key = keys[t];
        unsigned p = (unsigned)key;
        float score = __uint_as_float(~(unsigned)(key >> 32));
        bool v = score > CONF_T;
        float o0 = 0, o1 = 0, o2 = 0, o3 = 0, o4 = 0, o5 = 0;
        float f0 = 0, f1 = 0, f2 = 0, f3 = 0;
        if (v) {
            const float* xp = x + ((size_t)b * NPRED + p) * 85;
            float xc = xp[0], yc = xp[1], w = xp[2], h = xp[3];
            float hw = w * 0.5f, hh = h * 0.5f;
            o0 = xc - hw; o1 = yc - hh; o2 = xc + hw; o3 = yc + hh;
            o4 = score;
            float cf = (float)cls[(size_t)b * NPRED + p];
            o5 = cf;
            float co = cf * MAXWH;
            f0 = o0 + co; f1 = o1 + co; f2 = o2 + co; f3 = o3 + co;
        }
        size_t d6 = ((size_t)b * NTOP + t) * 6;
        det[d6 + 0] = o0; det[d6 + 1] = o1; det[d6 + 2] = o2;
        det[d6 + 3] = o3; det[d6 + 4] = o4; det[d6 + 5] = o5;
        size_t d4 = ((size_t)b * NTOP + t) * 4;
        offb[d4 + 0] = f0; offb[d4 + 1] = f1; offb[d4 + 2] = f2; offb[d4 + 3] = f3;
        valid[(size_t)b * NTOP + t] = v ? 1u : 0u;
    }
}

// ---------------------------------------------------------------------------
// K5: 1000x1000 IoU bitmask. Lanes <-> consecutive rows; columns are
// broadcast LDS reads (conflict-free). grid = 8 batches x 32 row-groups.
// ---------------------------------------------------------------------------
__global__ __launch_bounds__(256) void k_iou(const float* __restrict__ offb,
                                             u64* __restrict__ mask) {
#pragma clang fp contract(off)
    __shared__ __align__(16) float4 bx4[NTOP];
    __shared__ float area[NTOP];
    const int b = blockIdx.x >> 5;
    const int rg = blockIdx.x & 31;
    const float4* ob = (const float4*)(offb + (size_t)b * NTOP * 4);
    for (int i = threadIdx.x; i < NTOP; i += 256) {
        float4 v = ob[i];
        bx4[i] = v;
        area[i] = (v.z - v.x) * (v.w - v.y);
    }
    __syncthreads();
    const int i = rg * 32 + (threadIdx.x & 31);
    const int q = threadIdx.x >> 5;            // 8 word-pairs
    if (i >= NTOP) return;
    float4 A = bx4[i];
    float areaA = area[i];
    u64* mrow = &mask[((size_t)b * NTOP + i) * 16];
    for (int wi = 0; wi < 2; ++wi) {
        int w = q * 2 + wi;
        u64 bits = 0;
        int c0 = w * 64;
        for (int cc = 0; cc < 64; ++cc) {
            int col = c0 + cc;
            if (col >= NTOP) break;
            float4 Bb = bx4[col];              // broadcast read
            float ltx = fmaxf(A.x, Bb.x), lty = fmaxf(A.y, Bb.y);
            float rbx = fminf(A.z, Bb.z), rby = fminf(A.w, Bb.w);
            float ww = fmaxf(rbx - ltx, 0.0f), hh = fmaxf(rby - lty, 0.0f);
            float inter = ww * hh;
            float iou = inter / (((areaA + area[col]) - inter) + 1e-9f);
            if (iou > IOU_THR && col != i) bits |= (1ULL << cc);
        }
        mrow[w] = bits;
    }
}

// ---------------------------------------------------------------------------
// K6: serial greedy scan, one wave per batch; rows double-buffered in regs;
// output write fused per group.
// ---------------------------------------------------------------------------
__device__ __forceinline__ u64 shfl_xor_u64(u64 v, int m) {
    int lo = __shfl_xor((int)(unsigned)v, m);
    int hi = __shfl_xor((int)(unsigned)(v >> 32), m);
    return ((u64)(unsigned)hi << 32) | (unsigned)lo;
}

__global__ __launch_bounds__(64) void k_scan(const u64* __restrict__ mask,
                                             const unsigned* __restrict__ valid,
                                             const float* __restrict__ det,
                                             float* __restrict__ out) {
    const int b = blockIdx.x;
    const int lane = threadIdx.x;
    const u64* mb = mask + (size_t)b * NTOP * 16;
    __shared__ u64 colw[64];
    u64 acc[16], cur[16], nxt[16];
#pragma unroll
    for (int w = 0; w < 16; ++w) acc[w] = 0;

    u64 vbs[16];
#pragma unroll
    for (int g = 0; g < 16; ++g) {
        int r = g * 64 + lane;
        unsigned vf = (r < NTOP) ? valid[(size_t)b * NTOP + r] : 0u;
        vbs[g] = __ballot(vf != 0);
    }
    {
        int r = lane;
        const u64* rp = mb + (size_t)r * 16;
#pragma unroll
        for (int w = 0; w < 16; ++w) cur[w] = rp[w];
    }

#pragma unroll
    for (int g = 0; g < 16; ++g) {
        if (g < 15) {                       // prefetch next group's rows
            int rn = (g + 1) * 64 + lane;
            if (rn < NTOP) {
                const u64* rp = mb + (size_t)rn * 16;
#pragma unroll
                for (int w = 0; w < 16; ++w) nxt[w] = rp[w];
            } else {
#pragma unroll
                for (int w = 0; w < 16; ++w) nxt[w] = 0;
            }
        }
        u64 S = acc[g];
        S |= shfl_xor_u64(S, 1);  S |= shfl_xor_u64(S, 2);  S |= shfl_xor_u64(S, 4);
        S |= shfl_xor_u64(S, 8);  S |= shfl_xor_u64(S, 16); S |= shfl_xor_u64(S, 32);

        colw[lane] = cur[g];
        __syncthreads();

        const u64 vb = vbs[g];
        u64 kb = 0;
        const int lim = (g == 15) ? (NTOP - 15 * 64) : 64;
#pragma unroll 8
        for (int tt = 0; tt < 64; ++tt) {
            if (tt >= lim) break;
            u64 m = colw[tt];
            bool sup = (S >> tt) & 1ULL;
            bool keep = (!sup) && ((vb >> tt) & 1ULL);
            S |= keep ? m : 0ULL;
            kb |= keep ? (1ULL << tt) : 0ULL;
        }
        bool mykeep = (kb >> lane) & 1ULL;
#pragma unroll
        for (int w = 0; w < 16; ++w) acc[w] |= mykeep ? cur[w] : 0ULL;

        int r = g * 64 + lane;              // fused masked output write
        if (r < NTOP) {
            const float* dp = det + ((size_t)b * NTOP + r) * 6;
            float* op = out + ((size_t)b * NTOP + r) * 6;
#pragma unroll
            for (int c2 = 0; c2 < 6; ++c2) {
                float v = dp[c2];
                op[c2] = mykeep ? v : 0.0f;
            }
        }
        __syncthreads();
#pragma unroll
        for (int w = 0; w < 16; ++w) cur[w] = nxt[w];
    }
}

// ---------------------------------------------------------------------------
extern "C" void kernel_launch(void* const* d_in, const int* in_sizes, int n_in,
                              void* d_out, int out_size, void* d_ws, size_t ws_size,
                              hipStream_t stream) {
    const float* x = (const float*)d_in[0];
    char* ws = (char*)d_ws;
    // layout (bytes):
    float* msc = (float*)(ws);                       //       0 .. 806400
    int* cls = (int*)(ws + 806400);                  //  806400 .. 1612800
    float* det = (float*)(ws + 1612800);             // 1612800 .. 1804800
    float* offb = (float*)(ws + 1804800);            // 1804800 .. 1932800
    unsigned* valid = (unsigned*)(ws + 1932800);     // 1932800 .. 1964800
    u64* mask = (u64*)(ws + 1964800);                // 1964800 .. 2988800
    // overlays inside the mask region (dead until k_iou, after k_sort consumed them):
    unsigned* hist = (unsigned*)(ws + 1964800);      // 8*1025*4 = 32800
    unsigned* cnt = (unsigned*)(ws + 1997600);       // 32
    int* Bv = (int*)(ws + 1997632);                  // 32
    u64* cand = (u64*)(ws + 1997664);                // 8*2048*8 = 131072

    hipMemsetAsync(hist, 0, 32832, stream);          // hist + cnt
    k_score<<<NB * SBPB, 128, 0, stream>>>(x, msc, cls, hist);
    k_boundary<<<1, 512, 0, stream>>>(hist, Bv);
    k_compact<<<NB * 99, 256, 0, stream>>>(msc, Bv, cnt, cand);
    k_sort<<<NB, 1024, 0, stream>>>(x, cls, cnt, cand, det, offb, valid);
    k_iou<<<NB * 32, 256, 0, stream>>>(offb, mask);
    k_scan<<<NB, 64, 0, stream>>>(mask, valid, det, (float*)d_out);
}

// Round 3
// 217.730 us; speedup vs baseline: 1.3902x; 1.1117x over previous
//
#include <hip/hip_runtime.h>
#include <stdint.h>

#define NB 8
#define NPRED 25200
#define NTOP 1000
#define NCLS 80
#define CONF_T 0.25f
#define IOU_THR 0.45f
#define MAXWH 4096.0f
#define CAP 2048
#define NBINS 1025
#define SBLK 128
#define SBPB 197   // ceil(25200/128): 197*128 = 25216

typedef unsigned long long u64;

// ---------------------------------------------------------------------------
// K1: score/class per pred + global histogram of score bits.
// Staging via global_load_lds width=16 (no VGPR round trip).
// ---------------------------------------------------------------------------
__global__ __launch_bounds__(128) void k_score(const float* __restrict__ x,
                                               float* __restrict__ msc,
                                               int* __restrict__ cls,
                                               unsigned* __restrict__ hist) {
#pragma clang fp contract(off)
    __shared__ __align__(16) float sm[SBLK * 85];
    const int b = blockIdx.x / SBPB;
    const int blk = blockIdx.x % SBPB;
    const int t = threadIdx.x;
    const int wave = t >> 6, lane = t & 63;
    const long long TOT4 = (long long)NB * NPRED * 85 / 4;  // 4,284,000
    const long long base4 = ((long long)b * NPRED + (long long)blk * SBLK) * 85 / 4;
    const float4* x4 = (const float4*)x;
    const int tile4 = SBLK * 85 / 4;  // 2720

    for (int k = 0; k < 22; ++k) {
        int ib = k * 128 + wave * 64;      // wave-uniform lds base (float4 units)
        int fi = ib + lane;
        if (fi < tile4) {
            long long gi = base4 + fi;
            if (gi >= TOT4) gi = TOT4 - 1;  // tail clamp (outputs guarded below)
            __builtin_amdgcn_global_load_lds(
                (const __attribute__((address_space(1))) void*)(x4 + gi),
                (__attribute__((address_space(3))) void*)(sm + (size_t)ib * 4),
                16, 0, 0);
        }
    }
    __syncthreads();

    int pred = blk * SBLK + t;
    if (pred < NPRED) {
        const float* p = &sm[t * 85];
        float obj = p[4];
        float best = p[5];
        int bid = 0;
        for (int c = 1; c < NCLS; ++c) {
            float v = p[5 + c];
            if (v > best) { best = v; bid = c; }  // strict >: first occurrence
        }
        float score = obj * best;
        int q = b * NPRED + pred;
        msc[q] = (score > CONF_T) ? score : -1.0f;
        cls[q] = bid;
        if (score > CONF_T) {
            int bin = (int)(__float_as_uint(score) >> 14) - 0xFA00;
            bin = bin < 0 ? 0 : (bin > 1024 ? 1024 : bin);
            atomicAdd(&hist[b * NBINS + bin], 1u);
        }
    }
}

// ---------------------------------------------------------------------------
// K2 (fused): per-batch boundary-bin + compact-into-LDS + bitonic sort of
// <=2048 candidates (1024 threads) + gather top-1000.
// Key = (~score_bits << 32) | idx : ascending sort = descending score,
// ascending index on ties (stable top_k semantics).
// ---------------------------------------------------------------------------
__global__ __launch_bounds__(1024) void k_sort(const float* __restrict__ x,
                                               const float* __restrict__ msc,
                                               const int* __restrict__ cls,
                                               const unsigned* __restrict__ hist,
                                               float* __restrict__ det,
                                               float* __restrict__ offb,
                                               unsigned* __restrict__ valid) {
#pragma clang fp contract(off)
    __shared__ u64 keys[CAP];
    __shared__ int sB;
    __shared__ unsigned lcnt;
    const int b = blockIdx.x, t = threadIdx.x;
    const float* ms = msc + (size_t)b * NPRED;

    if (t == 0) lcnt = 0;
    if (t < 64) {  // wave 0: suffix-count boundary bin B
        const int lane = t;
        const unsigned* h = hist + b * NBINS;
        const int hi2 = 1024 - 16 * lane;       // lane chunk: bins [hi2-15, hi2]
        unsigned sum = 0;
        for (int k = 0; k < 16; ++k) sum += h[hi2 - k];
        if (lane == 63) sum += h[0];
        unsigned v = sum;
        for (int d = 1; d < 64; d <<= 1) {
            unsigned o = __shfl_up(v, d);
            if (lane >= d) v += o;
        }
        unsigned excl = v - sum;                // count strictly above my chunk
        u64 ball = __ballot(v >= NTOP);
        int B = 0;
        if (ball != 0) {
            int sel = __builtin_ctzll(ball);
            if (lane == sel) {
                unsigned run = excl;
                for (int k = 0; k < 16; ++k) {
                    run += h[hi2 - k];
                    if (run >= NTOP) { B = hi2 - k; break; }
                }
            }
            B = __shfl(B, sel);
        }
        if (lane == 0) sB = B;
    }
    __syncthreads();
    const int B = sB;

    // compact candidates (bin >= B) into LDS
    for (int p = t; p < NPRED; p += 1024) {
        float s = ms[p];
        if (s > CONF_T) {
            unsigned bits = __float_as_uint(s);
            int bin = (int)(bits >> 14) - 0xFA00;
            bin = bin < 0 ? 0 : (bin > 1024 ? 1024 : bin);
            if (bin >= B) {
                unsigned slot = atomicAdd(&lcnt, 1u);
                if (slot < CAP)
                    keys[slot] = ((u64)(~bits) << 32) | (unsigned)p;
            }
        }
    }
    __syncthreads();
    unsigned c = lcnt; if (c > CAP) c = CAP;
    for (int i = (int)c + t; i < CAP; i += 1024) keys[i] = ~0ULL;
    __syncthreads();

    // bitonic sort CAP keys ascending; 1 compare-exchange per thread per round
    for (unsigned k = 2; k <= CAP; k <<= 1) {
        for (unsigned j = k >> 1; j > 0; j >>= 1) {
            unsigned i = (((unsigned)t & ~(j - 1)) << 1) | ((unsigned)t & (j - 1));
            unsigned pi = i | j;
            bool up = ((i & k) == 0);
            u64 a = keys[i], d = keys[pi];
            bool sw = up ? (a > d) : (a < d);
            if (sw) { keys[i] = d; keys[pi] = a; }
            __syncthreads();
        }
    }

    // gather top-1000 -> det rows, class-offset boxes, valid flags
    if (t < NTOP) {
        u64 key = keys[t];
        unsigned p = (unsigned)key;
        float score = __uint_as_float(~(unsigned)(key >> 32));
        bool v = score > CONF_T;
        float o0 = 0, o1 = 0, o2 = 0, o3 = 0, o4 = 0, o5 = 0;
        float f0 = 0, f1 = 0, f2 = 0, f3 = 0;
        if (v) {
            const float* xp = x + ((size_t)b * NPRED + p) * 85;
            float xc = xp[0], yc = xp[1], w = xp[2], h = xp[3];
            float hw = w * 0.5f, hh = h * 0.5f;
            o0 = xc - hw; o1 = yc - hh; o2 = xc + hw; o3 = yc + hh;
            o4 = score;
            float cf = (float)cls[(size_t)b * NPRED + p];
            o5 = cf;
            float co = cf * MAXWH;
            f0 = o0 + co; f1 = o1 + co; f2 = o2 + co; f3 = o3 + co;
        }
        size_t d6 = ((size_t)b * NTOP + t) * 6;
        det[d6 + 0] = o0; det[d6 + 1] = o1; det[d6 + 2] = o2;
        det[d6 + 3] = o3; det[d6 + 4] = o4; det[d6 + 5] = o5;
        size_t d4 = ((size_t)b * NTOP + t) * 4;
        offb[d4 + 0] = f0; offb[d4 + 1] = f1; offb[d4 + 2] = f2; offb[d4 + 3] = f3;
        valid[(size_t)b * NTOP + t] = v ? 1u : 0u;
    }
}

// ---------------------------------------------------------------------------
// K3: 1000x1000 IoU bitmask. Lanes <-> consecutive rows; columns are
// broadcast LDS reads (conflict-free). grid = 8 batches x 32 row-groups.
// ---------------------------------------------------------------------------
__global__ __launch_bounds__(256) void k_iou(const float* __restrict__ offb,
                                             u64* __restrict__ mask) {
#pragma clang fp contract(off)
    __shared__ __align__(16) float4 bx4[NTOP];
    __shared__ float area[NTOP];
    const int b = blockIdx.x >> 5;
    const int rg = blockIdx.x & 31;
    const float4* ob = (const float4*)(offb + (size_t)b * NTOP * 4);
    for (int i = threadIdx.x; i < NTOP; i += 256) {
        float4 v = ob[i];
        bx4[i] = v;
        area[i] = (v.z - v.x) * (v.w - v.y);
    }
    __syncthreads();
    const int i = rg * 32 + (threadIdx.x & 31);
    const int q = threadIdx.x >> 5;            // 8 word-pairs
    if (i >= NTOP) return;
    float4 A = bx4[i];
    float areaA = area[i];
    u64* mrow = &mask[((size_t)b * NTOP + i) * 16];
    for (int wi = 0; wi < 2; ++wi) {
        int w = q * 2 + wi;
        u64 bits = 0;
        int c0 = w * 64;
        for (int cc = 0; cc < 64; ++cc) {
            int col = c0 + cc;
            if (col >= NTOP) break;
            float4 Bb = bx4[col];              // broadcast read
            float ltx = fmaxf(A.x, Bb.x), lty = fmaxf(A.y, Bb.y);
            float rbx = fminf(A.z, Bb.z), rby = fminf(A.w, Bb.w);
            float ww = fmaxf(rbx - ltx, 0.0f), hh = fmaxf(rby - lty, 0.0f);
            float inter = ww * hh;
            float iou = inter / (((areaA + area[col]) - inter) + 1e-9f);
            if (iou > IOU_THR && col != i) bits |= (1ULL << cc);
        }
        mrow[w] = bits;
    }
}

// ---------------------------------------------------------------------------
// K4: serial greedy scan, one wave per batch. Chain state (S, kb) is
// wave-uniform; feed it via v_readlane (constant lane, fully unrolled) so the
// serial chain is pure SALU/VALU — NO LDS in the chain (round-2's 61 us was
// 1024 x ds_read latency). Mask rows prefetched 2 groups ahead in registers.
// ---------------------------------------------------------------------------
__device__ __forceinline__ u64 shfl_xor_u64(u64 v, int m) {
    int lo = __shfl_xor((int)(unsigned)v, m);
    int hi = __shfl_xor((int)(unsigned)(v >> 32), m);
    return ((u64)(unsigned)hi << 32) | (unsigned)lo;
}

__global__ __launch_bounds__(64) void k_scan(const u64* __restrict__ mask,
                                             const unsigned* __restrict__ valid,
                                             const float* __restrict__ det,
                                             float* __restrict__ out) {
    const int b = blockIdx.x;
    const int lane = threadIdx.x;
    const u64* mb = mask + (size_t)b * NTOP * 16;
    u64 acc[16];
    u64 buf[3][16];
#pragma unroll
    for (int w = 0; w < 16; ++w) acc[w] = 0;

    u64 vbs[16];
#pragma unroll
    for (int g = 0; g < 16; ++g) {
        int r = g * 64 + lane;
        unsigned vf = (r < NTOP) ? valid[(size_t)b * NTOP + r] : 0u;
        vbs[g] = __ballot(vf != 0);   // wave-uniform -> SGPRs
    }

    auto loadgrp = [&](int g, u64* dst) {
        int r = g * 64 + lane;
        if (r < NTOP) {
            const u64* rp = mb + (size_t)r * 16;
#pragma unroll
            for (int w = 0; w < 16; ++w) dst[w] = rp[w];
        } else {
#pragma unroll
            for (int w = 0; w < 16; ++w) dst[w] = 0;
        }
    };
    loadgrp(0, buf[0]);
    loadgrp(1, buf[1]);

#pragma unroll
    for (int g = 0; g < 16; ++g) {
        if (g + 2 < 16) loadgrp(g + 2, buf[(g + 2) % 3]);
        u64* cur = buf[g % 3];

        // wave-uniform suppression word for this group from prior keeps
        u64 S = acc[g];
        S |= shfl_xor_u64(S, 1);  S |= shfl_xor_u64(S, 2);  S |= shfl_xor_u64(S, 4);
        S |= shfl_xor_u64(S, 8);  S |= shfl_xor_u64(S, 16); S |= shfl_xor_u64(S, 32);

        const u64 vb = vbs[g];
        const int mlo = (int)(unsigned)cur[g];
        const int mhi = (int)(unsigned)(cur[g] >> 32);
        u64 kb = 0;
#pragma unroll
        for (int tt = 0; tt < 64; ++tt) {
            unsigned lo = (unsigned)__builtin_amdgcn_readlane(mlo, tt);
            unsigned hi = (unsigned)__builtin_amdgcn_readlane(mhi, tt);
            u64 m = ((u64)hi << 32) | lo;
            u64 bit = 1ULL << tt;
            bool keep = ((S & bit) == 0) && ((vb & bit) != 0);
            S |= keep ? m : 0ULL;       // serial chain: pure ALU on uniforms
            kb |= keep ? bit : 0ULL;
        }
        bool mykeep = (kb >> lane) & 1ULL;
#pragma unroll
        for (int w = 0; w < 16; ++w) acc[w] |= mykeep ? cur[w] : 0ULL;

        int r = g * 64 + lane;          // fused masked output write
        if (r < NTOP) {
            const float* dp = det + ((size_t)b * NTOP + r) * 6;
            float* op = out + ((size_t)b * NTOP + r) * 6;
#pragma unroll
            for (int c2 = 0; c2 < 6; ++c2) {
                float v = dp[c2];
                op[c2] = mykeep ? v : 0.0f;
            }
        }
    }
}

// ---------------------------------------------------------------------------
extern "C" void kernel_launch(void* const* d_in, const int* in_sizes, int n_in,
                              void* d_out, int out_size, void* d_ws, size_t ws_size,
                              hipStream_t stream) {
    const float* x = (const float*)d_in[0];
    char* ws = (char*)d_ws;
    // layout (bytes):
    float* msc = (float*)(ws);                       //       0 .. 806400
    int* cls = (int*)(ws + 806400);                  //  806400 .. 1612800
    float* det = (float*)(ws + 1612800);             // 1612800 .. 1804800
    float* offb = (float*)(ws + 1804800);            // 1804800 .. 1932800
    unsigned* valid = (unsigned*)(ws + 1932800);     // 1932800 .. 1964800
    u64* mask = (u64*)(ws + 1964800);                // 1964800 .. 2988800
    // hist overlays the mask region (consumed by k_sort before k_iou writes):
    unsigned* hist = (unsigned*)(ws + 1964800);      // 8*1025*4 = 32800

    hipMemsetAsync(hist, 0, 32800, stream);
    k_score<<<NB * SBPB, 128, 0, stream>>>(x, msc, cls, hist);
    k_sort<<<NB, 1024, 0, stream>>>(x, msc, cls, hist, det, offb, valid);
    k_iou<<<NB * 32, 256, 0, stream>>>(offb, mask);
    k_scan<<<NB, 64, 0, stream>>>(mask, valid, det, (float*)d_out);
}